// Round 8
// baseline (269.985 us; speedup 1.0000x reference)
//
#include <hip/hip_runtime.h>

// DynamicFC: out[b,o,h,w] = sum_i w[b,o,i] * x[b,i,h,w] + bias[b,o]
// Batched GEMM per b: M=Cout=512, N=HW=784, K=Cin=512, fp32 in/out.
// R10 vs R9 (arc: R3-R9 prove the RA never funds a register-payload
// pipeline (VGPR stuck <=104) and lockstep blocks stall in phase; per
// block-step ~4800cy vs ~140cy of MFMA. Fix: pipeline with NO register
// payload):
//  - A staged as RAW FP32 via global_load_lds (async DMA, double-buffered):
//    issued for tile t+1 BEFORE compute(t); fenced by one explicit
//    vmcnt(0) AFTER compute+B-write. No regs in flight -> the compiler
//    cannot re-sink it. fp32->bf16 cvt moves to fragment assembly.
//  - DMA dest must be linear (rule #21) -> XOR-swizzle the GLOBAL source
//    chunk (c ^= row&7, 16B chunks) and apply the same XOR on the frag
//    ds_read_b128 address: A-reads become bank-balanced, A-writes are DMA.
//  - A is wave-private (each wave DMAs/reads its own 32 rows); only B
//    (k-transpose, shared) needs the barrier. B keeps R7's verified
//    register-micro-transpose path (bf16, LSTR 40).
//  - One raw s_barrier + lgkmcnt(0) per K-step; counted vmcnt for B regs
//    (compiler dependency-driven); explicit vmcnt(0) only for the DMA.
//  - 256-thr blocks, 128x112 tile, LDS ~50KB -> 3 blocks/CU, grid 1792.

#define CIN  512
#define COUT 512
#define HW   784      // 28*28 = 7*112
#define BM   128
#define BN   112
#define BK   32
#define LSTR 40       // B: 32 + 8 pad bf16 (80B row)

typedef __bf16 bf16_t;
typedef __bf16 bf16x8 __attribute__((ext_vector_type(8)));
typedef __bf16 bf16x4 __attribute__((ext_vector_type(4)));
typedef float  f32x4  __attribute__((ext_vector_type(4)));

__device__ __forceinline__ bf16x8 pack8(f32x4 a, f32x4 b) {
    bf16x8 r;
    r[0] = (bf16_t)a[0]; r[1] = (bf16_t)a[1];
    r[2] = (bf16_t)a[2]; r[3] = (bf16_t)a[3];
    r[4] = (bf16_t)b[0]; r[5] = (bf16_t)b[1];
    r[6] = (bf16_t)b[2]; r[7] = (bf16_t)b[3];
    return r;
}

// Async 16B global->LDS DMA. Global addr is PER-LANE; LDS dest is
// wave-uniform base + lane*16 (HW). Size must be the literal 16.
__device__ __forceinline__ void async_cp16(const float* g, float* l) {
    __builtin_amdgcn_global_load_lds(
        (const __attribute__((address_space(1))) unsigned int*)g,
        (__attribute__((address_space(3))) unsigned int*)l,
        16, 0, 0);
}

__global__ __launch_bounds__(256, 3) void dynfc_kernel(
    const float* __restrict__ x,     // [64][512][784]
    const float* __restrict__ w,     // [64][512][512]
    const float* __restrict__ bias,  // [64][512]
    float* __restrict__ out)         // [64][512][784]
{
    // A: fp32, [128 rows][32 floats] packed (128B rows), source-swizzled.
    __shared__ float  AsmF[2][BM * BK];    // 2 x 16 KB
    __shared__ bf16_t Bsm[2][BN * LSTR];   // 2 x 8.75 KB
    __shared__ float  bias_sm[BM];         // 0.5 KB   (total ~50.2 KB)

    // XCD swizzle: whole batches per XCD so W+X re-reads hit that XCD's L2.
    const int bid   = blockIdx.x;        // 0..1791
    const int xcd   = bid & 7;
    const int j     = bid >> 3;          // 0..223
    const int batch = xcd + 8 * (j / 28);
    const int trem  = j % 28;            // 4 m-tiles * 7 n-tiles
    const int tm    = trem / 7;
    const int tn    = trem % 7;
    const int m0    = tm * BM;
    const int n0    = tn * BN;

    const int tid  = threadIdx.x;
    const int lane = tid & 63;
    const int wid  = tid >> 6;
    const int wm   = wid * 32;           // wave's private 32-row A slice
    const int l15  = lane & 15;
    const int quad = lane >> 4;

    const float* xb = x + (size_t)batch * CIN * HW;
    const float* wb = w + (size_t)batch * COUT * CIN;

    if (tid < 32) {
        f32x4 bv = *(const f32x4*)(bias + batch * COUT + m0 + tid * 4);
        *(f32x4*)&bias_sm[tid * 4] = bv;
    }

    // B staging (R7-verified): kg = tid&7 (k-group of 4), ng = tid>>3
    // (col-group of 4); 224 active threads; write banks 4-way (~free).
    const int  kg      = tid & 7;        // 0..7
    const int  ng      = tid >> 3;       // 0..31
    const bool bactive = (ng < 28);      // 28*4 = 112 cols exactly

    const float* bsrc = xb + (size_t)(kg * 4) * HW + n0 + ng * 4;

    // A DMA source: lane (lane>>3 = row in 8-row group, lane&7 = chunk);
    // source chunk XOR row&7 so frag reads are bank-balanced while the
    // LDS dest stays linear. LDS[r][c] = G[r][c ^ (r&7)] (16B chunks).
    const float* agbase = wb + (size_t)(m0 + wm + (lane >> 3)) * CIN
                             + (((lane & 7) ^ (lane >> 3)) << 2);

    f32x4 br[4];   // B in-flight regs (only pipeline payload: 16 regs)

#define GLL_A(t, sbuf) do {                                                   \
        _Pragma("unroll")                                                     \
        for (int g_ = 0; g_ < 4; g_++)                                        \
            async_cp16(agbase + (t) * BK + (size_t)(g_ * 8) * CIN,            \
                       &AsmF[sbuf][(wm + g_ * 8) * BK]);                      \
    } while (0)

#define LOAD_B(t) do {                                                        \
        if (bactive) {                                                        \
            const float* bp_ = bsrc + (size_t)((t) * BK) * HW;                \
            br[0] = *(const f32x4*)(bp_);                                     \
            br[1] = *(const f32x4*)(bp_ + HW);                                \
            br[2] = *(const f32x4*)(bp_ + 2 * HW);                            \
            br[3] = *(const f32x4*)(bp_ + 3 * HW);                            \
        }                                                                     \
    } while (0)

#define WRITE_B(sbuf) do {                                                    \
        if (bactive) {                                                        \
            bf16_t* Bb_ = &Bsm[sbuf][0];                                      \
            _Pragma("unroll")                                                 \
            for (int nn = 0; nn < 4; nn++) {                                  \
                bf16x4 c_;                                                    \
                c_[0] = (bf16_t)br[0][nn]; c_[1] = (bf16_t)br[1][nn];         \
                c_[2] = (bf16_t)br[2][nn]; c_[3] = (bf16_t)br[3][nn];         \
                *(bf16x4*)&Bsm[sbuf][(ng * 4 + nn) * LSTR + kg * 4] = c_;     \
            }                                                                 \
            (void)Bb_;                                                        \
        }                                                                     \
    } while (0)

#define COMPUTE(sbuf) do {                                                    \
        const float*  Af_ = &AsmF[sbuf][0];                                   \
        const bf16_t* Bb_ = &Bsm[sbuf][0];                                    \
        bf16x8 af_[2], bf_[7];                                                \
        const int sw_ = l15 & 7;                                              \
        _Pragma("unroll")                                                     \
        for (int i = 0; i < 2; i++) {                                         \
            const int ro_ = (wm + i * 16 + l15) * BK;                         \
            f32x4 lo_ = *(const f32x4*)&Af_[ro_ + ((( 2*quad   ) ^ sw_) << 2)]; \
            f32x4 hi_ = *(const f32x4*)&Af_[ro_ + ((( 2*quad+1 ) ^ sw_) << 2)]; \
            af_[i] = pack8(lo_, hi_);                                         \
        }                                                                     \
        _Pragma("unroll")                                                     \
        for (int j2 = 0; j2 < 7; j2++)                                        \
            bf_[j2] = *(const bf16x8*)&Bb_[(j2 * 16 + l15) * LSTR + quad * 8];\
        __builtin_amdgcn_s_setprio(1);                                        \
        _Pragma("unroll")                                                     \
        for (int i = 0; i < 2; i++)                                           \
            _Pragma("unroll")                                                 \
            for (int j2 = 0; j2 < 7; j2++)                                    \
                acc[i][j2] = __builtin_amdgcn_mfma_f32_16x16x32_bf16(af_[i], bf_[j2], acc[i][j2], 0, 0, 0); \
        __builtin_amdgcn_s_setprio(0);                                        \
    } while (0)

    f32x4 acc[2][7] = {};

    // ---- prologue: tile 0 into buf0 (A via DMA, B via regs) ----
    LOAD_B(0);
    GLL_A(0, 0);
    WRITE_B(0);                                   // counted vmcnt for br
    asm volatile("s_waitcnt vmcnt(0)" ::: "memory");   // A DMA landed
    asm volatile("s_waitcnt lgkmcnt(0)" ::: "memory");
    __builtin_amdgcn_s_barrier();

    #pragma unroll
    for (int t = 0; t < 16; ++t) {
        const int s = t & 1;

        // ---- issue next tile's loads FIRST (DMA has no reg payload,
        // B holds 16 regs); latency hides under compute(t) ----
        if (t + 1 < 16) {
            LOAD_B(t + 1);
            GLL_A(t + 1, s ^ 1);
        }
        __builtin_amdgcn_sched_barrier(0);

        // ---- compute tile t: A frags (swizzled f32 reads + cvt), B frags,
        // 14 MFMA ----
        COMPUTE(s);
        __builtin_amdgcn_sched_barrier(0);

        // ---- finish next tile's staging: B cvt+write (vmcnt counted so
        // the A-DMA stays outstanding), then fence the DMA ----
        if (t + 1 < 16) WRITE_B(s ^ 1);
        asm volatile("s_waitcnt vmcnt(0)" ::: "memory");   // A(t+1) in LDS
        __builtin_amdgcn_sched_barrier(0);
        asm volatile("s_waitcnt lgkmcnt(0)" ::: "memory"); // ds_writes done
        __builtin_amdgcn_s_barrier();
        __builtin_amdgcn_sched_barrier(0);
    }

#undef GLL_A
#undef LOAD_B
#undef WRITE_B
#undef COMPUTE

    // ---- epilogue: add bias, plain store (7*112 == 784, no guard) ----
    // C/D layout: col = lane&15, row = quad*4 + r
    float* ob = out + (size_t)batch * COUT * HW;
    #pragma unroll
    for (int j2 = 0; j2 < 7; j2++) {
        const int n = n0 + j2 * 16 + l15;
        #pragma unroll
        for (int i = 0; i < 2; i++) {
            #pragma unroll
            for (int r = 0; r < 4; r++) {
                const int m = wm + i * 16 + quad * 4 + r;
                ob[(size_t)(m0 + m) * HW + n] = acc[i][j2][r] + bias_sm[m];
            }
        }
    }
}

extern "C" void kernel_launch(void* const* d_in, const int* in_sizes, int n_in,
                              void* d_out, int out_size, void* d_ws, size_t ws_size,
                              hipStream_t stream) {
    (void)in_sizes; (void)n_in; (void)d_ws; (void)ws_size; (void)out_size;
    const float* x    = (const float*)d_in[0];
    const float* w    = (const float*)d_in[1];
    const float* bias = (const float*)d_in[2];
    float* out        = (float*)d_out;

    dim3 grid(64 * 4 * 7);   // 64 batches * 4 m-tiles * 7 n-tiles
    dim3 block(256);
    dynfc_kernel<<<grid, block, 0, stream>>>(x, w, bias, out);
}